// Round 1
// baseline (30.125 us; speedup 1.0000x reference)
//
#include <hip/hip_runtime.h>

// CrossNet (DCN cross layers): B=16384, D=1024, L=3
//   s_b     = sum_d xl[b,d] * w[l,d]
//   xl[b,d] = x0[b,d] * s_b + bias[l,d] + xl[b,d]
// Memory-bound: ideal traffic = read x (64 MiB) + write out (64 MiB).
// One block (256 threads) per row; row lives entirely in registers (float4/thread).

#define CN_B 16384
#define CN_D 1024
#define CN_L 3

__global__ __launch_bounds__(256) void crossnet_kernel(
    const float* __restrict__ x,
    const float* __restrict__ w,
    const float* __restrict__ bias,
    float* __restrict__ out) {
  const int row  = blockIdx.x;
  const int tid  = threadIdx.x;
  const int wave = tid >> 6;
  const int lane = tid & 63;

  const float4* xrow = reinterpret_cast<const float4*>(x + (size_t)row * CN_D);
  float4 x0 = xrow[tid];
  float4 xl = x0;

  __shared__ float red[4];  // one partial per wave

  #pragma unroll
  for (int l = 0; l < CN_L; ++l) {
    const float4 wl = reinterpret_cast<const float4*>(w    + l * CN_D)[tid];
    const float4 bl = reinterpret_cast<const float4*>(bias + l * CN_D)[tid];

    // per-thread partial dot (4 elems)
    float p = xl.x * wl.x + xl.y * wl.y + xl.z * wl.z + xl.w * wl.w;

    // 64-lane wave reduction
    #pragma unroll
    for (int off = 32; off > 0; off >>= 1)
      p += __shfl_down(p, off, 64);

    if (lane == 0) red[wave] = p;
    __syncthreads();

    // every thread sums the 4 wave partials in the same order -> identical s
    const float s = red[0] + red[1] + red[2] + red[3];

    xl.x = x0.x * s + bl.x + xl.x;
    xl.y = x0.y * s + bl.y + xl.y;
    xl.z = x0.z * s + bl.z + xl.z;
    xl.w = x0.w * s + bl.w + xl.w;

    __syncthreads();  // red[] reused next layer
  }

  reinterpret_cast<float4*>(out + (size_t)row * CN_D)[tid] = xl;
}

extern "C" void kernel_launch(void* const* d_in, const int* in_sizes, int n_in,
                              void* d_out, int out_size, void* d_ws, size_t ws_size,
                              hipStream_t stream) {
  const float* x    = (const float*)d_in[0];
  const float* w    = (const float*)d_in[1];
  const float* bias = (const float*)d_in[2];
  float* out        = (float*)d_out;

  crossnet_kernel<<<CN_B, 256, 0, stream>>>(x, w, bias, out);
}

// Round 2
// 30.000 us; speedup vs baseline: 1.0042x; 1.0042x over previous
//
#include <hip/hip_runtime.h>

// CrossNet (DCN cross layers): B=16384, D=1024, L=3
//   s_b     = sum_d xl[b,d] * w[l,d]
//   xl[b,d] = x0[b,d] * s_b + bias[l,d] + xl[b,d]
//
// R1: one WAVE per row (64 lanes x 16 floats). Reduction = 6-step shfl_xor
// butterfly -> no LDS, no __syncthreads, fully independent waves.
// 4 rows per 256-thread block; w/bias (24 KiB total) stay L1/L2 resident.

#define CN_B 16384
#define CN_D 1024
#define CN_L 3
#define ROWS_PER_BLOCK 4

__global__ __launch_bounds__(256, 4) void crossnet_kernel(
    const float* __restrict__ x,
    const float* __restrict__ w,
    const float* __restrict__ bias,
    float* __restrict__ out) {
  const int tid  = threadIdx.x;
  const int wave = tid >> 6;
  const int lane = tid & 63;
  const int row  = blockIdx.x * ROWS_PER_BLOCK + wave;

  // lane k-th float4 at index k*64 + lane -> each load is 64 contiguous float4s (1 KiB)
  const float4* xrow = reinterpret_cast<const float4*>(x + (size_t)row * CN_D);
  float4 x0[4], xl[4];
  #pragma unroll
  for (int k = 0; k < 4; ++k) {
    x0[k] = xrow[k * 64 + lane];
    xl[k] = x0[k];
  }

  #pragma unroll
  for (int l = 0; l < CN_L; ++l) {
    const float4* wrow = reinterpret_cast<const float4*>(w    + l * CN_D);
    const float4* brow = reinterpret_cast<const float4*>(bias + l * CN_D);
    float4 wl[4], bl[4];
    #pragma unroll
    for (int k = 0; k < 4; ++k) {
      wl[k] = wrow[k * 64 + lane];
      bl[k] = brow[k * 64 + lane];
    }

    // per-lane partial dot over 16 elements
    float p = 0.0f;
    #pragma unroll
    for (int k = 0; k < 4; ++k) {
      p += xl[k].x * wl[k].x;
      p += xl[k].y * wl[k].y;
      p += xl[k].z * wl[k].z;
      p += xl[k].w * wl[k].w;
    }

    // 64-lane butterfly: every lane ends with the identical full sum
    #pragma unroll
    for (int off = 32; off > 0; off >>= 1)
      p += __shfl_xor(p, off, 64);

    #pragma unroll
    for (int k = 0; k < 4; ++k) {
      xl[k].x = x0[k].x * p + bl[k].x + xl[k].x;
      xl[k].y = x0[k].y * p + bl[k].y + xl[k].y;
      xl[k].z = x0[k].z * p + bl[k].z + xl[k].z;
      xl[k].w = x0[k].w * p + bl[k].w + xl[k].w;
    }
  }

  float4* orow = reinterpret_cast<float4*>(out + (size_t)row * CN_D);
  #pragma unroll
  for (int k = 0; k < 4; ++k)
    orow[k * 64 + lane] = xl[k];
}

extern "C" void kernel_launch(void* const* d_in, const int* in_sizes, int n_in,
                              void* d_out, int out_size, void* d_ws, size_t ws_size,
                              hipStream_t stream) {
  const float* x    = (const float*)d_in[0];
  const float* w    = (const float*)d_in[1];
  const float* bias = (const float*)d_in[2];
  float* out        = (float*)d_out;

  crossnet_kernel<<<CN_B / ROWS_PER_BLOCK, 256, 0, stream>>>(x, w, bias, out);
}

// Round 3
// 25.548 us; speedup vs baseline: 1.1792x; 1.1743x over previous
//
#include <hip/hip_runtime.h>

// CrossNet (DCN cross layers): B=16384, D=1024, L=3
//   s_b     = sum_d xl[b,d] * w[l,d]
//   xl[b,d] = x0[b,d] * s_b + bias[l,d] + xl[b,d]
//
// R2: TWO rows per wave. w/bias fragments loaded once per wave, reused for
// both rows (halves per-row L1 traffic); the two rows' dot->butterfly->update
// chains are independent (ILP=2 through the serial shfl reduction).
// 64 lanes x 16 floats per row, all state in registers, no LDS, no barriers.

#define CN_B 16384
#define CN_D 1024
#define CN_L 3
#define ROWS_PER_WAVE 2
#define WAVES_PER_BLOCK 4
#define ROWS_PER_BLOCK (ROWS_PER_WAVE * WAVES_PER_BLOCK)

__global__ __launch_bounds__(256, 4) void crossnet_kernel(
    const float* __restrict__ x,
    const float* __restrict__ w,
    const float* __restrict__ bias,
    float* __restrict__ out) {
  const int tid  = threadIdx.x;
  const int wave = tid >> 6;
  const int lane = tid & 63;
  const int row0 = (blockIdx.x * WAVES_PER_BLOCK + wave) * ROWS_PER_WAVE;

  const float4* xr0 = reinterpret_cast<const float4*>(x + (size_t)row0 * CN_D);
  const float4* xr1 = reinterpret_cast<const float4*>(x + (size_t)(row0 + 1) * CN_D);

  float4 x0a[4], xla[4], x0b[4], xlb[4];
  #pragma unroll
  for (int k = 0; k < 4; ++k) {
    x0a[k] = xr0[k * 64 + lane];
    x0b[k] = xr1[k * 64 + lane];
    xla[k] = x0a[k];
    xlb[k] = x0b[k];
  }

  #pragma unroll
  for (int l = 0; l < CN_L; ++l) {
    const float4* wrow = reinterpret_cast<const float4*>(w    + l * CN_D);
    const float4* brow = reinterpret_cast<const float4*>(bias + l * CN_D);
    float4 wl[4], bl[4];
    #pragma unroll
    for (int k = 0; k < 4; ++k) {
      wl[k] = wrow[k * 64 + lane];
      bl[k] = brow[k * 64 + lane];
    }

    // independent partial dots for the two rows
    float pa = 0.0f, pb = 0.0f;
    #pragma unroll
    for (int k = 0; k < 4; ++k) {
      pa += xla[k].x * wl[k].x; pb += xlb[k].x * wl[k].x;
      pa += xla[k].y * wl[k].y; pb += xlb[k].y * wl[k].y;
      pa += xla[k].z * wl[k].z; pb += xlb[k].z * wl[k].z;
      pa += xla[k].w * wl[k].w; pb += xlb[k].w * wl[k].w;
    }

    // two interleaved 64-lane butterflies (independent -> ILP=2)
    #pragma unroll
    for (int off = 32; off > 0; off >>= 1) {
      pa += __shfl_xor(pa, off, 64);
      pb += __shfl_xor(pb, off, 64);
    }

    #pragma unroll
    for (int k = 0; k < 4; ++k) {
      xla[k].x = x0a[k].x * pa + bl[k].x + xla[k].x;
      xla[k].y = x0a[k].y * pa + bl[k].y + xla[k].y;
      xla[k].z = x0a[k].z * pa + bl[k].z + xla[k].z;
      xla[k].w = x0a[k].w * pa + bl[k].w + xla[k].w;
      xlb[k].x = x0b[k].x * pb + bl[k].x + xlb[k].x;
      xlb[k].y = x0b[k].y * pb + bl[k].y + xlb[k].y;
      xlb[k].z = x0b[k].z * pb + bl[k].z + xlb[k].z;
      xlb[k].w = x0b[k].w * pb + bl[k].w + xlb[k].w;
    }
  }

  float4* or0 = reinterpret_cast<float4*>(out + (size_t)row0 * CN_D);
  float4* or1 = reinterpret_cast<float4*>(out + (size_t)(row0 + 1) * CN_D);
  #pragma unroll
  for (int k = 0; k < 4; ++k) {
    or0[k * 64 + lane] = xla[k];
    or1[k * 64 + lane] = xlb[k];
  }
}

extern "C" void kernel_launch(void* const* d_in, const int* in_sizes, int n_in,
                              void* d_out, int out_size, void* d_ws, size_t ws_size,
                              hipStream_t stream) {
  const float* x    = (const float*)d_in[0];
  const float* w    = (const float*)d_in[1];
  const float* bias = (const float*)d_in[2];
  float* out        = (float*)d_out;

  crossnet_kernel<<<CN_B / ROWS_PER_BLOCK, 256, 0, stream>>>(x, w, bias, out);
}